// Round 2
// baseline (604.007 us; speedup 1.0000x reference)
//
#include <hip/hip_runtime.h>
#include <math.h>

// VQ quantizer: z [N,64] fp32, codebook [512,64] fp32.
// out layout (all fp32): q_ste [N*64] | loss [1] | ids-as-float [N]
//
// R1 post-mortem: LDS-broadcast of codewords made the kernel LDS-pipe-bound
// (16 ds_read_b128 x 12cyc = 192W cyc/CU vs 64W VALU cyc/SIMD -> VALUBusy 39%).
// R2: codeword fetch moved to UNIFORM global loads (SMEM s_load or coalesced
// same-address VMEM — either way off the LDS pipe). Arithmetic is bit-identical
// to the verified R1 kernel (absmax 0.0): same chain pairing, same
// d2 = fmaf(-2,dot,z2) + c2, strict '<' ascending-k argmin.

constexpr int D   = 64;
constexpr int D4  = 16;     // float4s per row
constexpr int K   = 512;
constexpr int BLOCK  = 256;
constexpr int ROWS_PER_BLOCK = 2 * BLOCK; // 2 rows per thread

#define FMA4(acc, zz, cc) do { \
  acc = fmaf((zz).x, (cc).x, acc); \
  acc = fmaf((zz).y, (cc).y, acc); \
  acc = fmaf((zz).z, (cc).z, acc); \
  acc = fmaf((zz).w, (cc).w, acc); } while (0)

__global__ __launch_bounds__(BLOCK)
void vq_main(const float* __restrict__ z, const float* __restrict__ cbk,
             float* __restrict__ out, float* __restrict__ lossAcc, int N)
{
    __shared__ float  c2s[K];               // 2 KB
    __shared__ float  wsum[BLOCK / 64];

    const int tid = threadIdx.x;
    const long rowBase = (long)blockIdx.x * ROWS_PER_BLOCK;
    const long r0 = rowBase + tid;
    const long r1 = rowBase + tid + BLOCK;

    // Codeword squared norms — identical chain to R1.
    for (int k = tid; k < K; k += BLOCK) {
        const float4* c4 = (const float4*)(cbk + (long)k * D);
        float s = 0.f;
        #pragma unroll
        for (int i = 0; i < D4; ++i) { float4 c = c4[i]; FMA4(s, c, c); }
        c2s[k] = s;
    }

    // z rows into registers (128 VGPRs) + row norms — identical chains to R1.
    float4 z0[D4], z1[D4];
    {
        const float4* zp0 = (const float4*)(z + r0 * D);
        const float4* zp1 = (const float4*)(z + r1 * D);
        #pragma unroll
        for (int i = 0; i < D4; ++i) { z0[i] = zp0[i]; z1[i] = zp1[i]; }
    }
    float z2_0 = 0.f, z2_1 = 0.f;
    #pragma unroll
    for (int i = 0; i < D4; ++i) { FMA4(z2_0, z0[i], z0[i]); }
    #pragma unroll
    for (int i = 0; i < D4; ++i) { FMA4(z2_1, z1[i], z1[i]); }

    __syncthreads(); // c2s ready

    float best0 = INFINITY, best1 = INFINITY;
    int   bi0 = 0, bi1 = 0;

    for (int k = 0; k < K; ++k) {
        // Wave-uniform codeword fetch from global (SMEM/L1-broadcast path;
        // LDS pipe stays free for c2s only).
        const float4* __restrict__ crow = (const float4*)(cbk + (long)k * D);
        float4 c[D4];
        #pragma unroll
        for (int i = 0; i < D4; ++i) c[i] = crow[i];

        // 4 independent FMA chains — same pairing/order as R1.
        float a0 = 0.f, b0 = 0.f, a1 = 0.f, b1 = 0.f;
        #pragma unroll
        for (int i = 0; i < D4; i += 2) {
            FMA4(a0, z0[i],     c[i]);
            FMA4(b0, z0[i + 1], c[i + 1]);
            FMA4(a1, z1[i],     c[i]);
            FMA4(b1, z1[i + 1], c[i + 1]);
        }
        float dot0 = a0 + b0;
        float dot1 = a1 + b1;
        float c2 = c2s[k];
        float d0 = fmaf(-2.f, dot0, z2_0) + c2;
        float d1 = fmaf(-2.f, dot1, z2_1) + c2;
        if (d0 < best0) { best0 = d0; bi0 = k; }
        if (d1 < best1) { best1 = d1; bi1 = k; }
    }

    // Epilogue — identical to R1.
    float lacc = 0.f;
    {
        const float4* qp = (const float4*)(cbk + (long)bi0 * D);
        float4* o = (float4*)(out + r0 * D);
        #pragma unroll
        for (int i = 0; i < D4; ++i) {
            float4 q = qp[i], zz = z0[i], u, qs;
            u.x = q.x - zz.x; u.y = q.y - zz.y; u.z = q.z - zz.z; u.w = q.w - zz.w;
            qs.x = zz.x + u.x; qs.y = zz.y + u.y; qs.z = zz.z + u.z; qs.w = zz.w + u.w;
            FMA4(lacc, u, u);
            o[i] = qs;
        }
    }
    {
        const float4* qp = (const float4*)(cbk + (long)bi1 * D);
        float4* o = (float4*)(out + r1 * D);
        #pragma unroll
        for (int i = 0; i < D4; ++i) {
            float4 q = qp[i], zz = z1[i], u, qs;
            u.x = q.x - zz.x; u.y = q.y - zz.y; u.z = q.z - zz.z; u.w = q.w - zz.w;
            qs.x = zz.x + u.x; qs.y = zz.y + u.y; qs.z = zz.z + u.z; qs.w = zz.w + u.w;
            FMA4(lacc, u, u);
            o[i] = qs;
        }
    }

    float* idsOut = out + (long)N * D + 1;
    idsOut[r0] = (float)bi0;
    idsOut[r1] = (float)bi1;

    // Loss: wave shuffle reduce -> per-wave LDS -> one atomicAdd per block.
    #pragma unroll
    for (int off = 32; off > 0; off >>= 1) lacc += __shfl_down(lacc, off, 64);
    if ((tid & 63) == 0) wsum[tid >> 6] = lacc;
    __syncthreads();
    if (tid == 0) {
        float s = wsum[0] + wsum[1] + wsum[2] + wsum[3];
        atomicAdd(lossAcc, s);
    }
}

__global__ void vq_finalize(float* __restrict__ out,
                            const float* __restrict__ lossAcc, int N)
{
    out[(long)N * D] = 1.25f * (lossAcc[0] / (float)((long)N * D));
}

extern "C" void kernel_launch(void* const* d_in, const int* in_sizes, int n_in,
                              void* d_out, int out_size, void* d_ws, size_t ws_size,
                              hipStream_t stream)
{
    const float* z   = (const float*)d_in[0];
    const float* cbk = (const float*)d_in[1];
    float* out = (float*)d_out;
    float* ws  = (float*)d_ws;
    const int N = in_sizes[0] / D;

    hipMemsetAsync(ws, 0, sizeof(float), stream);
    const int blocks = N / ROWS_PER_BLOCK;
    vq_main<<<blocks, BLOCK, 0, stream>>>(z, cbk, out, ws, N);
    vq_finalize<<<1, 1, 0, stream>>>(out, ws, N);
}

// Round 3
// 452.938 us; speedup vs baseline: 1.3335x; 1.3335x over previous
//
#include <hip/hip_runtime.h>
#include <math.h>

// VQ quantizer: z [N,64] fp32, codebook [512,64] fp32.
// out layout (all fp32): q_ste [N*64] | loss [1] | ids-as-float [N]
//
// R1: LDS broadcast of codewords -> LDS-pipe-bound (192 cyc/codeword/wave).
// R2: uniform global loads -> compiler kept them vector -> VMEM-pipe-bound
//     (256 cyc/codeword/wave; 537/440 = 256/192 confirmed the model).
// R3: codeword fetched ONCE PER WAVE into SGPRs via s_load_dwordx16 inline
//     asm (4 SMEM instrs/codeword, separate pipe, ~4 B/cyc/CU). v_fma_f32
//     takes the codeword as its one SGPR operand -> fetch cost leaves the
//     VALU/LDS/VMEM pipes entirely. rpt=1 for 16 waves/CU latency hiding.
// Arithmetic chains are bit-identical to the verified R1/R2 kernels
// (absmax 0.0): even chunks->a0, odd->b0, dot=a0+b0,
// d2 = fmaf(-2,dot,z2)+c2, strict '<' ascending-k argmin.

constexpr int D   = 64;
constexpr int D4  = 16;     // float4s per row
constexpr int K   = 512;
constexpr int BLOCK  = 256;
constexpr int ROWS_PER_BLOCK = BLOCK;   // 1 row per thread

typedef float v16f __attribute__((ext_vector_type(16)));

#define FMA4(acc, zz, cc) do { \
  acc = fmaf((zz).x, (cc).x, acc); \
  acc = fmaf((zz).y, (cc).y, acc); \
  acc = fmaf((zz).z, (cc).z, acc); \
  acc = fmaf((zz).w, (cc).w, acc); } while (0)

// One 4-float chunk of the dot product, codeword from an SGPR-resident
// 16-float vector (v_fma_f32 dst, s, v, v : 1 SGPR operand is legal).
#define CHUNK_FMA(acc, zreg, vec, off) do { \
  acc = fmaf((zreg).x, (vec)[(off)+0], acc); \
  acc = fmaf((zreg).y, (vec)[(off)+1], acc); \
  acc = fmaf((zreg).z, (vec)[(off)+2], acc); \
  acc = fmaf((zreg).w, (vec)[(off)+3], acc); } while (0)

__global__ __launch_bounds__(BLOCK)
void vq_main(const float* __restrict__ z, const float* __restrict__ cbk,
             float* __restrict__ out, float* __restrict__ lossAcc, int N)
{
    __shared__ float c2s[K];            // 2 KB
    __shared__ float wsum[BLOCK / 64];

    const int tid = threadIdx.x;
    const long r0 = (long)blockIdx.x * ROWS_PER_BLOCK + tid;

    // Codeword squared norms — identical chain to R1/R2.
    for (int k = tid; k < K; k += BLOCK) {
        const float4* c4 = (const float4*)(cbk + (long)k * D);
        float s = 0.f;
        #pragma unroll
        for (int i = 0; i < D4; ++i) { float4 c = c4[i]; FMA4(s, c, c); }
        c2s[k] = s;
    }

    // z row into registers (64 VGPRs) + row norm — identical chain.
    float4 z0[D4];
    {
        const float4* zp0 = (const float4*)(z + r0 * D);
        #pragma unroll
        for (int i = 0; i < D4; ++i) { z0[i] = zp0[i]; }
    }
    float z2_0 = 0.f;
    #pragma unroll
    for (int i = 0; i < D4; ++i) { FMA4(z2_0, z0[i], z0[i]); }

    __syncthreads(); // c2s ready

    float best0 = INFINITY;
    int   bi0 = 0;

    const float* cp = cbk;
    #pragma unroll 1
    for (int k = 0; k < K; ++k) {
        // Whole codeword -> 64 SGPRs, once per wave (SMEM pipe).
        v16f ca, cb, cc, cd;
        asm volatile("s_load_dwordx16 %0, %1, 0x0"  : "=&s"(ca) : "s"(cp));
        asm volatile("s_load_dwordx16 %0, %1, 0x40" : "=&s"(cb) : "s"(cp));
        asm volatile("s_load_dwordx16 %0, %1, 0x80" : "=&s"(cc) : "s"(cp));
        asm volatile("s_load_dwordx16 %0, %1, 0xc0" : "=&s"(cd) : "s"(cp));
        // Data-dependence-carried wait: load -> wait -> FMA cannot reorder.
        asm volatile("s_waitcnt lgkmcnt(0)"
                     : "+s"(ca), "+s"(cb), "+s"(cc), "+s"(cd));

        // Two independent chains, same chunk->chain mapping as R1/R2:
        // even chunks -> a0, odd chunks -> b0.
        float a0 = 0.f, b0 = 0.f;
        CHUNK_FMA(a0, z0[0],  ca, 0);  CHUNK_FMA(b0, z0[1],  ca, 4);
        CHUNK_FMA(a0, z0[2],  ca, 8);  CHUNK_FMA(b0, z0[3],  ca, 12);
        CHUNK_FMA(a0, z0[4],  cb, 0);  CHUNK_FMA(b0, z0[5],  cb, 4);
        CHUNK_FMA(a0, z0[6],  cb, 8);  CHUNK_FMA(b0, z0[7],  cb, 12);
        CHUNK_FMA(a0, z0[8],  cc, 0);  CHUNK_FMA(b0, z0[9],  cc, 4);
        CHUNK_FMA(a0, z0[10], cc, 8);  CHUNK_FMA(b0, z0[11], cc, 12);
        CHUNK_FMA(a0, z0[12], cd, 0);  CHUNK_FMA(b0, z0[13], cd, 4);
        CHUNK_FMA(a0, z0[14], cd, 8);  CHUNK_FMA(b0, z0[15], cd, 12);

        float dot0 = a0 + b0;
        float d0 = fmaf(-2.f, dot0, z2_0) + c2s[k];
        if (d0 < best0) { best0 = d0; bi0 = k; }
        cp += D;
    }

    // Epilogue — identical ops to R1/R2.
    float lacc = 0.f;
    {
        const float4* qp = (const float4*)(cbk + (long)bi0 * D);
        float4* o = (float4*)(out + r0 * D);
        #pragma unroll
        for (int i = 0; i < D4; ++i) {
            float4 q = qp[i], zz = z0[i], u, qs;
            u.x = q.x - zz.x; u.y = q.y - zz.y; u.z = q.z - zz.z; u.w = q.w - zz.w;
            qs.x = zz.x + u.x; qs.y = zz.y + u.y; qs.z = zz.z + u.z; qs.w = zz.w + u.w;
            FMA4(lacc, u, u);
            o[i] = qs;
        }
    }

    float* idsOut = out + (long)N * D + 1;
    idsOut[r0] = (float)bi0;

    // Loss: wave shuffle reduce -> per-wave LDS -> one atomicAdd per block.
    #pragma unroll
    for (int off = 32; off > 0; off >>= 1) lacc += __shfl_down(lacc, off, 64);
    if ((tid & 63) == 0) wsum[tid >> 6] = lacc;
    __syncthreads();
    if (tid == 0) {
        float s = wsum[0] + wsum[1] + wsum[2] + wsum[3];
        atomicAdd(lossAcc, s);
    }
}

__global__ void vq_finalize(float* __restrict__ out,
                            const float* __restrict__ lossAcc, int N)
{
    out[(long)N * D] = 1.25f * (lossAcc[0] / (float)((long)N * D));
}

extern "C" void kernel_launch(void* const* d_in, const int* in_sizes, int n_in,
                              void* d_out, int out_size, void* d_ws, size_t ws_size,
                              hipStream_t stream)
{
    const float* z   = (const float*)d_in[0];
    const float* cbk = (const float*)d_in[1];
    float* out = (float*)d_out;
    float* ws  = (float*)d_ws;
    const int N = in_sizes[0] / D;

    hipMemsetAsync(ws, 0, sizeof(float), stream);
    const int blocks = N / ROWS_PER_BLOCK;
    vq_main<<<blocks, BLOCK, 0, stream>>>(z, cbk, out, ws, N);
    vq_finalize<<<1, 1, 0, stream>>>(out, ws, N);
}

// Round 5
// 377.419 us; speedup vs baseline: 1.6004x; 1.2001x over previous
//
#include <hip/hip_runtime.h>
#include <math.h>

// VQ quantizer: z [N,64] fp32, codebook [512,64] fp32.
// out layout (all fp32): q_ste [N*64] | loss [1] | ids-as-float [N]
//
// R1: LDS codeword broadcast -> LDS-pipe-bound (440us, VALUBusy 39%).
// R2: uniform vector loads   -> VMEM-pipe-bound (537us, VALUBusy 24%).
// R3: s_load_dwordx16 SGPR codewords -> fetch off all vector pipes, but the
//     per-iteration s_waitcnt lgkmcnt(0) exposes SMEM latency at only
//     4 waves/SIMD -> latency-bound (453us, VALUBusy 33%).
// R4: K-split x2 (waves 0-1: k<256, waves 2-3: k>=256, same 128 rows) ->
//     8192 waves hide the SMEM stall. COMPILE FIX (R5): kbeg derives from
//     tid>>7 which divergence analysis can't prove uniform -> pointer fell
//     into VGPRs -> s_load rejected. Launder via readfirstlane so cp stays
//     an SGPR pair. Inner loop bit-identical to verified R3 (absmax 0.0);
//     merge uses strict '<' so ties keep lower k == numpy first-min.

constexpr int D   = 64;
constexpr int D4  = 16;     // float4s per row
constexpr int K   = 512;
constexpr int KHALF = 256;
constexpr int BLOCK  = 256;
constexpr int ROWS_PER_BLOCK = 128;   // 1 row per thread, 2 waves per row

typedef float v16f __attribute__((ext_vector_type(16)));

#define FMA4(acc, zz, cc) do { \
  acc = fmaf((zz).x, (cc).x, acc); \
  acc = fmaf((zz).y, (cc).y, acc); \
  acc = fmaf((zz).z, (cc).z, acc); \
  acc = fmaf((zz).w, (cc).w, acc); } while (0)

#define CHUNK_FMA(acc, zreg, vec, off) do { \
  acc = fmaf((zreg).x, (vec)[(off)+0], acc); \
  acc = fmaf((zreg).y, (vec)[(off)+1], acc); \
  acc = fmaf((zreg).z, (vec)[(off)+2], acc); \
  acc = fmaf((zreg).w, (vec)[(off)+3], acc); } while (0)

__global__ __launch_bounds__(BLOCK)
void vq_main(const float* __restrict__ z, const float* __restrict__ cbk,
             float* __restrict__ out, float* __restrict__ lossAcc, int N)
{
    __shared__ float c2s[K];                 // 2 KB
    __shared__ float mbest[ROWS_PER_BLOCK];  // high-half merge buffers
    __shared__ int   mbi[ROWS_PER_BLOCK];
    __shared__ float wsum[BLOCK / 64];

    const int tid   = threadIdx.x;
    const int local = tid & 127;        // row within block (waves 0&2 share)
    const int khalf = tid >> 7;         // wave-uniform: 0 for waves 0-1, 1 for 2-3
    const long r0   = (long)blockIdx.x * ROWS_PER_BLOCK + local;

    // Codeword squared norms — identical chain to R1-R3.
    for (int k = tid; k < K; k += BLOCK) {
        const float4* c4 = (const float4*)(cbk + (long)k * D);
        float s = 0.f;
        #pragma unroll
        for (int i = 0; i < D4; ++i) { float4 c = c4[i]; FMA4(s, c, c); }
        c2s[k] = s;
    }

    // z row into registers (64 VGPRs) + row norm — identical chain.
    float4 z0[D4];
    {
        const float4* zp0 = (const float4*)(z + r0 * D);
        #pragma unroll
        for (int i = 0; i < D4; ++i) { z0[i] = zp0[i]; }
    }
    float z2_0 = 0.f;
    #pragma unroll
    for (int i = 0; i < D4; ++i) { FMA4(z2_0, z0[i], z0[i]); }

    __syncthreads(); // c2s ready

    float best0 = INFINITY;
    int   bi0 = 0;

    // khalf is wave-uniform in fact; readfirstlane makes it COMPILER-KNOWN
    // uniform so cp lives in an SGPR pair (required by s_load_dwordx16).
    const int kbeg_s = __builtin_amdgcn_readfirstlane(khalf * KHALF);
    const int kbeg   = khalf * KHALF;   // per-lane copy for c2s/argmin index
    const float* cp  = cbk + (long)kbeg_s * D;

    #pragma unroll 1
    for (int kk = 0; kk < KHALF; ++kk) {
        const int k = kbeg + kk;
        // Whole codeword -> 64 SGPRs, once per wave (SMEM pipe).
        v16f ca, cb, cc, cd;
        asm volatile("s_load_dwordx16 %0, %1, 0x0"  : "=&s"(ca) : "s"(cp));
        asm volatile("s_load_dwordx16 %0, %1, 0x40" : "=&s"(cb) : "s"(cp));
        asm volatile("s_load_dwordx16 %0, %1, 0x80" : "=&s"(cc) : "s"(cp));
        asm volatile("s_load_dwordx16 %0, %1, 0xc0" : "=&s"(cd) : "s"(cp));
        asm volatile("s_waitcnt lgkmcnt(0)"
                     : "+s"(ca), "+s"(cb), "+s"(cc), "+s"(cd));

        // Two independent chains — identical mapping to R1-R3.
        float a0 = 0.f, b0 = 0.f;
        CHUNK_FMA(a0, z0[0],  ca, 0);  CHUNK_FMA(b0, z0[1],  ca, 4);
        CHUNK_FMA(a0, z0[2],  ca, 8);  CHUNK_FMA(b0, z0[3],  ca, 12);
        CHUNK_FMA(a0, z0[4],  cb, 0);  CHUNK_FMA(b0, z0[5],  cb, 4);
        CHUNK_FMA(a0, z0[6],  cb, 8);  CHUNK_FMA(b0, z0[7],  cb, 12);
        CHUNK_FMA(a0, z0[8],  cc, 0);  CHUNK_FMA(b0, z0[9],  cc, 4);
        CHUNK_FMA(a0, z0[10], cc, 8);  CHUNK_FMA(b0, z0[11], cc, 12);
        CHUNK_FMA(a0, z0[12], cd, 0);  CHUNK_FMA(b0, z0[13], cd, 4);
        CHUNK_FMA(a0, z0[14], cd, 8);  CHUNK_FMA(b0, z0[15], cd, 12);

        float dot0 = a0 + b0;
        float d0 = fmaf(-2.f, dot0, z2_0) + c2s[k];
        if (d0 < best0) { best0 = d0; bi0 = k; }
        cp += D;
    }

    // Publish high half, merge in low half. Tie (==) keeps half 0 = lower k,
    // matching numpy argmin first-min semantics.
    if (khalf == 1) { mbest[local] = best0; mbi[local] = bi0; }
    __syncthreads();

    float lacc = 0.f;
    if (khalf == 0) {
        float dhi = mbest[local];
        int   ihi = mbi[local];
        if (dhi < best0) { best0 = dhi; bi0 = ihi; }

        // Epilogue — identical ops to R1-R3.
        const float4* qp = (const float4*)(cbk + (long)bi0 * D);
        float4* o = (float4*)(out + r0 * D);
        #pragma unroll
        for (int i = 0; i < D4; ++i) {
            float4 q = qp[i], zz = z0[i], u, qs;
            u.x = q.x - zz.x; u.y = q.y - zz.y; u.z = q.z - zz.z; u.w = q.w - zz.w;
            qs.x = zz.x + u.x; qs.y = zz.y + u.y; qs.z = zz.z + u.z; qs.w = zz.w + u.w;
            FMA4(lacc, u, u);
            o[i] = qs;
        }

        float* idsOut = out + (long)N * D + 1;
        idsOut[r0] = (float)bi0;
    }

    // Loss: wave shuffle reduce -> per-wave LDS -> one atomicAdd per block.
    // (waves 2-3 contribute 0.)
    #pragma unroll
    for (int off = 32; off > 0; off >>= 1) lacc += __shfl_down(lacc, off, 64);
    if ((tid & 63) == 0) wsum[tid >> 6] = lacc;
    __syncthreads();
    if (tid == 0) {
        float s = wsum[0] + wsum[1] + wsum[2] + wsum[3];
        atomicAdd(lossAcc, s);
    }
}

__global__ void vq_finalize(float* __restrict__ out,
                            const float* __restrict__ lossAcc, int N)
{
    out[(long)N * D] = 1.25f * (lossAcc[0] / (float)((long)N * D));
}

extern "C" void kernel_launch(void* const* d_in, const int* in_sizes, int n_in,
                              void* d_out, int out_size, void* d_ws, size_t ws_size,
                              hipStream_t stream)
{
    const float* z   = (const float*)d_in[0];
    const float* cbk = (const float*)d_in[1];
    float* out = (float*)d_out;
    float* ws  = (float*)d_ws;
    const int N = in_sizes[0] / D;

    hipMemsetAsync(ws, 0, sizeof(float), stream);
    const int blocks = N / ROWS_PER_BLOCK;
    vq_main<<<blocks, BLOCK, 0, stream>>>(z, cbk, out, ws, N);
    vq_finalize<<<1, 1, 0, stream>>>(out, ws, N);
}